// Round 1
// 969.151 us; speedup vs baseline: 1.0494x; 1.0494x over previous
//
#include <hip/hip_runtime.h>

#define S_LEN 2048
#define NH    32
#define NKVH  8
#define HD    64
#define HALFD 32
#define QKSCALE 0.125f

using short8 = __attribute__((ext_vector_type(8))) short;
using f32x4  = __attribute__((ext_vector_type(4))) float;

__device__ __forceinline__ unsigned short f2bf(float f) {
  unsigned int x = __builtin_bit_cast(unsigned int, f);
  x += 0x7fffu + ((x >> 16) & 1u);
  return (unsigned short)(x >> 16);
}

__device__ __forceinline__ f32x4 mfma_bf16(short8 a, short8 b, f32x4 c) {
  return __builtin_amdgcn_mfma_f32_16x16x32_bf16(a, b, c, 0, 0, 0);
}

__device__ __forceinline__ void gll16(const unsigned short* g, unsigned short* l) {
  __builtin_amdgcn_global_load_lds(
      (const __attribute__((address_space(1))) unsigned int*)g,
      (__attribute__((address_space(3))) unsigned int*)l, 16, 0, 0);
}

// ---------------- elementwise f32 -> bf16 cast ----------------
__global__ void cast_x(const float* __restrict__ in, unsigned short* __restrict__ out) {
  long i = ((long)blockIdx.x * 256 + threadIdx.x) * 4;
  float4 v = *(const float4*)(in + i);
  ushort4 o;
  o.x = f2bf(v.x); o.y = f2bf(v.y); o.z = f2bf(v.z); o.w = f2bf(v.w);
  *(ushort4*)(out + i) = o;
}

// ---------------- transpose + cast: out[c][r] = bf16(in[r][c]) ----------------
__global__ void transpose_cast(const float* __restrict__ in, unsigned short* __restrict__ out,
                               int in_rs, long in_zs, int out_rs, long out_zs) {
  __shared__ float t[32][33];
  const float* inp = in + (long)blockIdx.z * in_zs;
  unsigned short* outp = out + (long)blockIdx.z * out_zs;
  int r0 = blockIdx.y * 32, c0 = blockIdx.x * 32;
  for (int rr = threadIdx.y; rr < 32; rr += 8)
    t[rr][threadIdx.x] = inp[(long)(r0 + rr) * in_rs + c0 + threadIdx.x];
  __syncthreads();
  for (int rr = threadIdx.y; rr < 32; rr += 8)
    outp[(long)(c0 + rr) * out_rs + r0 + threadIdx.x] = f2bf(t[threadIdx.x][rr]);
}

// ---------------- m97-style GEMM body, now double-buffered (T3 minimum 2-phase) ----------------
// C(MxN,f32) = A(MxK) * BT(NxK)^T, 128x128 tile, BK=32.
// As/Bs point at [2][128*32] ushort regions (16 KB each, 32 KB total).
__device__ __forceinline__ void gemm128_body(const unsigned short* __restrict__ A,
                                             const unsigned short* __restrict__ BT,
                                             float* __restrict__ C, int M, int N, int K,
                                             int bx, int by,
                                             unsigned short* As, unsigned short* Bs) {
  int m0 = by * 128, n0 = bx * 128;
  int tid = threadIdx.x;
  int lane = tid & 63, wave = tid >> 6;
  int quad = lane >> 4, lanelo = lane & 15;
  int wm = wave & 1, wn = wave >> 1;
  // staging: each wave covers 16 rows x 32 k (1 KB) per gll16; row = wave*16 + (lane>>2), kchunk = lane&3
  const unsigned short* gA = A + (long)(m0 + wave * 16 + (lane >> 2)) * K + (lane & 3) * 8;
  const unsigned short* gB = BT + (long)(n0 + wave * 16 + (lane >> 2)) * K + (lane & 3) * 8;
  long rowjump = (long)64 * K;
  f32x4 zero = {0.f, 0.f, 0.f, 0.f};
  f32x4 acc[4][4];
#pragma unroll
  for (int i = 0; i < 4; i++)
#pragma unroll
    for (int j = 0; j < 4; j++) acc[i][j] = zero;

  // prologue: stage k0=0 into buffer 0, drain, barrier
  gll16(gA, As + wave * 512);
  gll16(gA + rowjump, As + 2048 + wave * 512);
  gll16(gB, Bs + wave * 512);
  gll16(gB + rowjump, Bs + 2048 + wave * 512);
  __syncthreads();

  int cur = 0;
  for (int k0 = 0; k0 < K; k0 += 32) {
    int kn = k0 + 32;
    if (kn < K) {  // prefetch next K-slab BEFORE computing current -> latency hides under MFMAs
      unsigned short* An = As + ((cur ^ 1) << 12);
      unsigned short* Bn = Bs + ((cur ^ 1) << 12);
      gll16(gA + kn, An + wave * 512);
      gll16(gA + rowjump + kn, An + 2048 + wave * 512);
      gll16(gB + kn, Bn + wave * 512);
      gll16(gB + rowjump + kn, Bn + 2048 + wave * 512);
    }
    const unsigned short* Ac = As + (cur << 12);
    const unsigned short* Bc = Bs + (cur << 12);
    short8 af[4], bfr[4];
#pragma unroll
    for (int mt = 0; mt < 4; mt++)
      af[mt] = *(const short8*)(Ac + (wm * 64 + mt * 16 + lanelo) * 32 + quad * 8);
#pragma unroll
    for (int nt = 0; nt < 4; nt++)
      bfr[nt] = *(const short8*)(Bc + (wn * 64 + nt * 16 + lanelo) * 32 + quad * 8);
#pragma unroll
    for (int mt = 0; mt < 4; mt++)
#pragma unroll
      for (int nt = 0; nt < 4; nt++)
        acc[mt][nt] = mfma_bf16(af[mt], bfr[nt], acc[mt][nt]);
    __syncthreads();  // drains prefetch vmcnt + protects buffer reuse (single barrier per step)
    cur ^= 1;
  }
#pragma unroll
  for (int mt = 0; mt < 4; mt++) {
    int crow = m0 + wm * 64 + mt * 16 + quad * 4;
#pragma unroll
    for (int nt = 0; nt < 4; nt++) {
      int ccol = n0 + wn * 64 + nt * 16 + lanelo;
#pragma unroll
      for (int r = 0; r < 4; r++)
        C[(long)(crow + r) * N + ccol] = acc[mt][nt][r];
    }
  }
}

__global__ __launch_bounds__(256) void gemm128(const unsigned short* __restrict__ A,
                                               const unsigned short* __restrict__ BT,
                                               float* __restrict__ C, int M, int N, int K) {
  __shared__ unsigned short As[2][4096];
  __shared__ unsigned short Bs[2][4096];
  gemm128_body(A, BT, C, M, N, K, blockIdx.x, blockIdx.y, &As[0][0], &Bs[0][0]);
}

// ---------------- RoPE: src(S, stride) f32 cols [off + h*64 ..] -> dst(nh, S, 64) bf16 ----------------
__global__ void rope_kernel(const float* __restrict__ src, const float* __restrict__ cosb,
                            const float* __restrict__ sinb, unsigned short* __restrict__ dst,
                            int nheads, int src_off, int src_stride) {
  long idx = (long)blockIdx.x * 256 + threadIdx.x;   // over S*nheads*32
  int d = (int)(idx & (HALFD - 1));
  long t = idx >> 5;
  int h = (int)(t % nheads);
  int s = (int)(t / nheads);
  float c = cosb[s * HALFD + d], sn = sinb[s * HALFD + d];
  long base = (long)s * src_stride + src_off + h * HD + d;
  float x1 = src[base], x2 = src[base + HALFD];
  long ob = ((long)h * S_LEN + s) * HD + d;
  dst[ob]         = f2bf(x1 * c - x2 * sn);
  dst[ob + HALFD] = f2bf(x2 * c + x1 * sn);
}

// ---------------- flash attention (no-max softmax): O (normalized) + 1/l per row ----------------
__global__ __launch_bounds__(256) void attn_flash(const unsigned short* __restrict__ qb,
                                                  const unsigned short* __restrict__ kb,
                                                  const unsigned short* __restrict__ vT,
                                                  const float* __restrict__ sinks,
                                                  unsigned short* __restrict__ ob,
                                                  float* __restrict__ linv) {
  __shared__ unsigned short plds[4][16 * 72];   // wave-private 16x64 bf16 P tile, stride 72
  int qt = 31 - blockIdx.x;                     // heavy tiles first
  int h = blockIdx.y, kvh = h >> 2;
  int lane = threadIdx.x & 63, wave = threadIdx.x >> 6;
  int quad = lane >> 4, lanelo = lane & 15;
  int q0 = qt * 64 + wave * 16;
  const unsigned short* qrow = qb + ((long)h * S_LEN + q0 + lanelo) * HD + quad * 8;
  short8 aq0 = *(const short8*)(qrow);
  short8 aq1 = *(const short8*)(qrow + HALFD);
  const unsigned short* kbase = kb + (long)kvh * S_LEN * HD;
  const unsigned short* vbase = vT + (long)kvh * HD * S_LEN;
  f32x4 zero = {0.f, 0.f, 0.f, 0.f};
  f32x4 oacc[4] = {zero, zero, zero, zero};
  float l[4] = {0.f, 0.f, 0.f, 0.f};
  unsigned short* pw = &plds[wave][0];

  for (int j0 = 0; j0 <= q0 + 15; j0 += 64) {
    f32x4 sc[4];
#pragma unroll
    for (int nd = 0; nd < 4; nd++) {
      const unsigned short* krow = kbase + (long)(j0 + nd * 16 + lanelo) * HD + quad * 8;
      short8 b0 = *(const short8*)(krow);
      short8 b1 = *(const short8*)(krow + HALFD);
      f32x4 c = mfma_bf16(aq0, b0, zero);
      sc[nd] = mfma_bf16(aq1, b1, c);
    }
#pragma unroll
    for (int nd = 0; nd < 4; nd++) {
      int col = j0 + nd * 16 + lanelo;
#pragma unroll
      for (int r = 0; r < 4; r++) {
        int row = q0 + quad * 4 + r;
        float e = (col <= row) ? __expf(sc[nd][r] * QKSCALE) : 0.f;
        l[r] += e;
        pw[(quad * 4 + r) * 72 + nd * 16 + lanelo] = f2bf(e);
      }
    }
    // wave-private LDS: no barrier needed, lgkmcnt ordering only
#pragma unroll
    for (int ks = 0; ks < 2; ks++) {
      short8 pa = *(const short8*)(&pw[lanelo * 72 + ks * 32 + quad * 8]);
#pragma unroll
      for (int nd = 0; nd < 4; nd++) {
        short8 vb = *(const short8*)(&vbase[(long)(nd * 16 + lanelo) * S_LEN + j0 + ks * 32 + quad * 8]);
        oacc[nd] = mfma_bf16(pa, vb, oacc[nd]);
      }
    }
  }
  float sink = sinks[h];
  float inv[4];
#pragma unroll
  for (int r = 0; r < 4; r++) {
    float s = l[r];
    s += __shfl_xor(s, 1, 64);
    s += __shfl_xor(s, 2, 64);
    s += __shfl_xor(s, 4, 64);
    s += __shfl_xor(s, 8, 64);
    s += __expf(sink);
    inv[r] = 1.f / s;
    if (lanelo == 0) linv[h * S_LEN + q0 + quad * 4 + r] = inv[r];
  }
#pragma unroll
  for (int nd = 0; nd < 4; nd++)
#pragma unroll
    for (int r = 0; r < 4; r++)
      ob[(long)(q0 + quad * 4 + r) * (NH * HD) + h * HD + nd * 16 + lanelo] = f2bf(oacc[nd][r] * inv[r]);
}

// ---------------- balanced prob writer body: recompute QK^T, p = exp(sc)*linv ----------------
__device__ __forceinline__ void probs_body(const unsigned short* __restrict__ qb,
                                           const unsigned short* __restrict__ kb,
                                           const float* __restrict__ linv,
                                           float* __restrict__ wout,
                                           int qt, int strip, int h, float* t) {
  int kvh = h >> 2;
  int lane = threadIdx.x & 63, wave = threadIdx.x >> 6;
  int quad = lane >> 4, lanelo = lane & 15;
  int q0 = qt * 64 + wave * 16;
  const unsigned short* qrow = qb + ((long)h * S_LEN + q0 + lanelo) * HD + quad * 8;
  short8 aq0 = *(const short8*)(qrow);
  short8 aq1 = *(const short8*)(qrow + HALFD);
  const unsigned short* kbase = kb + (long)kvh * S_LEN * HD;
  float inv[4];
#pragma unroll
  for (int r = 0; r < 4; r++) inv[r] = linv[h * S_LEN + q0 + quad * 4 + r];
  float* wb = wout + ((long)h * S_LEN + q0) * S_LEN;
  float* tw = t + wave * 1088;   // wave-private 16x64 f32 tile, stride 68
  f32x4 zero = {0.f, 0.f, 0.f, 0.f};
  int srow = lane >> 4, scol = (lane & 15) * 4;   // store mapping: 4 rows x 256B contiguous

  for (int jt = 0; jt < 8; jt++) {
    int j0 = strip * 512 + jt * 64;
    if (j0 > q0 + 15) {
      // fully above diagonal: zeros
      float4 z4 = {0.f, 0.f, 0.f, 0.f};
#pragma unroll
      for (int rg = 0; rg < 4; rg++)
        *(float4*)(&wb[(long)(rg * 4 + srow) * S_LEN + j0 + scol]) = z4;
      continue;
    }
    f32x4 sc[4];
#pragma unroll
    for (int nd = 0; nd < 4; nd++) {
      const unsigned short* krow = kbase + (long)(j0 + nd * 16 + lanelo) * HD + quad * 8;
      short8 b0 = *(const short8*)(krow);
      short8 b1 = *(const short8*)(krow + HALFD);
      f32x4 c = mfma_bf16(aq0, b0, zero);
      sc[nd] = mfma_bf16(aq1, b1, c);
    }
#pragma unroll
    for (int nd = 0; nd < 4; nd++) {
      int col = j0 + nd * 16 + lanelo;
#pragma unroll
      for (int r = 0; r < 4; r++) {
        int row = q0 + quad * 4 + r;
        float p = (col <= row) ? __expf(sc[nd][r] * QKSCALE) * inv[r] : 0.f;
        tw[(quad * 4 + r) * 68 + nd * 16 + lanelo] = p;
      }
    }
    // wave-private LDS transpose -> 256B-contiguous float4 stores
#pragma unroll
    for (int rg = 0; rg < 4; rg++) {
      int row = rg * 4 + srow;
      float4 v = *(float4*)(&tw[row * 68 + scol]);
      *(float4*)(&wb[(long)row * S_LEN + j0 + scol]) = v;
    }
  }
}

// ---------------- fused tail: blocks [0,256) = O-projection GEMM, [256,4352) = prob writer ----------------
// Both depend only on attn_flash outputs and write disjoint buffers; fusing lets the
// compute-bound GEMM run concurrently with the HBM-write-bound prob pass.
__global__ __launch_bounds__(256) void tail_fused(const unsigned short* __restrict__ ob,
                                                  const unsigned short* __restrict__ WoT,
                                                  float* __restrict__ out,
                                                  const unsigned short* __restrict__ qb,
                                                  const unsigned short* __restrict__ kb,
                                                  const float* __restrict__ linv,
                                                  float* __restrict__ wout) {
  __shared__ __align__(16) char smem[32768];   // gemm: 2x(2x4096 ushort); probs: 4x1088 f32 (17408 B)
  int bid = blockIdx.x;
  if (bid < 256) {
    gemm128_body(ob, WoT, out, 2048, 2048, 2048, bid & 15, bid >> 4,
                 (unsigned short*)smem, (unsigned short*)(smem + 16384));
  } else {
    int id = bid - 256;
    probs_body(qb, kb, linv, wout, id & 31, (id >> 5) & 3, id >> 7, (float*)smem);
  }
}

extern "C" void kernel_launch(void* const* d_in, const int* in_sizes, int n_in,
                              void* d_out, int out_size, void* d_ws, size_t ws_size,
                              hipStream_t stream) {
  const float* x     = (const float*)d_in[0];
  const float* cosb  = (const float*)d_in[1];
  const float* sinb  = (const float*)d_in[2];
  const float* Wq    = (const float*)d_in[4];
  const float* Wk    = (const float*)d_in[5];
  const float* Wv    = (const float*)d_in[6];
  const float* Wo    = (const float*)d_in[7];
  const float* sinks = (const float*)d_in[8];
  float* out  = (float*)d_out;
  float* wout = out + (long)S_LEN * (NH * HD);   // attn_weights after attn_output

  char* w = (char*)d_ws;
  unsigned short* xb     = (unsigned short*)(w);                 // 8 MB
  float*          linv   = (float*)(w);                          // reuses xb after G1
  unsigned short* WqkvT  = (unsigned short*)(w + (8l  << 20));   // 12 MB (3072 x 2048)
  unsigned short* WoT    = (unsigned short*)(w + (20l << 20));   // 8 MB
  float*          qkvf   = (float*)(w + (28l << 20));            // 24 MB (2048 x 3072)
  unsigned short* qb     = (unsigned short*)(w + (52l << 20));   // 8 MB
  unsigned short* kb     = (unsigned short*)(w + (60l << 20));   // 2 MB
  unsigned short* vT     = (unsigned short*)(w + (62l << 20));   // 2 MB
  unsigned short* ob     = (unsigned short*)(w + (64l << 20));   // 8 MB

  cast_x<<<4096, 256, 0, stream>>>(x, xb);
  transpose_cast<<<dim3(64, 64, 1), dim3(32, 8), 0, stream>>>(Wq, WqkvT, 2048, 0, 2048, 0);
  transpose_cast<<<dim3(16, 64, 1), dim3(32, 8), 0, stream>>>(Wk, WqkvT + (long)2048 * 2048, 512, 0, 2048, 0);
  transpose_cast<<<dim3(16, 64, 1), dim3(32, 8), 0, stream>>>(Wv, WqkvT + (long)2560 * 2048, 512, 0, 2048, 0);
  transpose_cast<<<dim3(64, 64, 1), dim3(32, 8), 0, stream>>>(Wo, WoT, 2048, 0, 2048, 0);
  // fused QKV projection: (2048x2048) x (3072x2048)^T -> (2048x3072)
  gemm128<<<dim3(24, 16), 256, 0, stream>>>(xb, WqkvT, qkvf, 2048, 3072, 2048);
  rope_kernel<<<8192, 256, 0, stream>>>(qkvf, cosb, sinb, qb, NH, 0, 3072);
  rope_kernel<<<2048, 256, 0, stream>>>(qkvf, cosb, sinb, kb, NKVH, 2048, 3072);
  // v part of qkvf (cols 2560..3071): (S, 8*64) f32 -> vT (8, 64, S) bf16
  transpose_cast<<<dim3(2, 64, 8), dim3(32, 8), 0, stream>>>(qkvf + 2560, vT, 3072, 64, 2048, (long)64 * 2048);
  attn_flash<<<dim3(32, 32), 256, 0, stream>>>(qb, kb, vT, sinks, ob, linv);
  // fused: O-projection GEMM (256 blocks) + prob writer (4096 blocks), concurrent
  tail_fused<<<4352, 256, 0, stream>>>(ob, WoT, out, qb, kb, linv, wout);
}

// Round 2
// 945.284 us; speedup vs baseline: 1.0759x; 1.0252x over previous
//
#include <hip/hip_runtime.h>

#define S_LEN 2048
#define NH    32
#define NKVH  8
#define HD    64
#define HALFD 32
#define QKSCALE 0.125f

using short8 = __attribute__((ext_vector_type(8))) short;
using f32x4  = __attribute__((ext_vector_type(4))) float;

__device__ __forceinline__ unsigned short f2bf(float f) {
  unsigned int x = __builtin_bit_cast(unsigned int, f);
  x += 0x7fffu + ((x >> 16) & 1u);
  return (unsigned short)(x >> 16);
}

__device__ __forceinline__ f32x4 mfma_bf16(short8 a, short8 b, f32x4 c) {
  return __builtin_amdgcn_mfma_f32_16x16x32_bf16(a, b, c, 0, 0, 0);
}

__device__ __forceinline__ void gll16(const unsigned short* g, unsigned short* l) {
  __builtin_amdgcn_global_load_lds(
      (const __attribute__((address_space(1))) unsigned int*)g,
      (__attribute__((address_space(3))) unsigned int*)l, 16, 0, 0);
}

// ---------------- fused prologue: cast_x + 4 weight transposes, block-range dispatch ----------------
// [0,4096): x f32 -> xb bf16          [4096,8192): Wq^T   [8192,9216): Wk^T
// [9216,10240): Wv^T                  [10240,14336): Wo^T
__global__ __launch_bounds__(256) void prologue(const float* __restrict__ x,
                                                unsigned short* __restrict__ xb,
                                                const float* __restrict__ Wq,
                                                const float* __restrict__ Wk,
                                                const float* __restrict__ Wv,
                                                const float* __restrict__ Wo,
                                                unsigned short* __restrict__ WqkvT,
                                                unsigned short* __restrict__ WoT) {
  int bid = blockIdx.x;
  if (bid < 4096) {
    long i = ((long)bid * 256 + threadIdx.x) * 4;
    float4 v = *(const float4*)(x + i);
    ushort4 o;
    o.x = f2bf(v.x); o.y = f2bf(v.y); o.z = f2bf(v.z); o.w = f2bf(v.w);
    *(ushort4*)(xb + i) = o;
    return;
  }
  __shared__ float t[32][33];
  const float* in; unsigned short* outp; int in_rs, out_rs, bx, by;
  if (bid < 8192)       { int id = bid - 4096;  in = Wq; outp = WqkvT;                      in_rs = 2048; out_rs = 2048; bx = id & 63; by = id >> 6; }
  else if (bid < 9216)  { int id = bid - 8192;  in = Wk; outp = WqkvT + (long)2048 * 2048;  in_rs = 512;  out_rs = 2048; bx = id & 15; by = id >> 4; }
  else if (bid < 10240) { int id = bid - 9216;  in = Wv; outp = WqkvT + (long)2560 * 2048;  in_rs = 512;  out_rs = 2048; bx = id & 15; by = id >> 4; }
  else                  { int id = bid - 10240; in = Wo; outp = WoT;                        in_rs = 2048; out_rs = 2048; bx = id & 63; by = id >> 6; }
  int tx = threadIdx.x & 31, ty = threadIdx.x >> 5;
  int r0 = by * 32, c0 = bx * 32;
  for (int rr = ty; rr < 32; rr += 8)
    t[rr][tx] = in[(long)(r0 + rr) * in_rs + c0 + tx];
  __syncthreads();
  for (int rr = ty; rr < 32; rr += 8)
    outp[(long)(c0 + rr) * out_rs + r0 + tx] = f2bf(t[tx][rr]);
}

// ---------------- m97-style GEMM body, double-buffered (T3 minimum 2-phase) ----------------
// C(MxN,f32) = A(MxK) * BT(NxK)^T, 128x128 tile, BK=32.
// As/Bs point at [2][128*32] ushort regions (16 KB each, 32 KB total).
__device__ __forceinline__ void gemm128_body(const unsigned short* __restrict__ A,
                                             const unsigned short* __restrict__ BT,
                                             float* __restrict__ C, int M, int N, int K,
                                             int bx, int by,
                                             unsigned short* As, unsigned short* Bs) {
  int m0 = by * 128, n0 = bx * 128;
  int tid = threadIdx.x;
  int lane = tid & 63, wave = tid >> 6;
  int quad = lane >> 4, lanelo = lane & 15;
  int wm = wave & 1, wn = wave >> 1;
  const unsigned short* gA = A + (long)(m0 + wave * 16 + (lane >> 2)) * K + (lane & 3) * 8;
  const unsigned short* gB = BT + (long)(n0 + wave * 16 + (lane >> 2)) * K + (lane & 3) * 8;
  long rowjump = (long)64 * K;
  f32x4 zero = {0.f, 0.f, 0.f, 0.f};
  f32x4 acc[4][4];
#pragma unroll
  for (int i = 0; i < 4; i++)
#pragma unroll
    for (int j = 0; j < 4; j++) acc[i][j] = zero;

  gll16(gA, As + wave * 512);
  gll16(gA + rowjump, As + 2048 + wave * 512);
  gll16(gB, Bs + wave * 512);
  gll16(gB + rowjump, Bs + 2048 + wave * 512);
  __syncthreads();

  int cur = 0;
  for (int k0 = 0; k0 < K; k0 += 32) {
    int kn = k0 + 32;
    if (kn < K) {
      unsigned short* An = As + ((cur ^ 1) << 12);
      unsigned short* Bn = Bs + ((cur ^ 1) << 12);
      gll16(gA + kn, An + wave * 512);
      gll16(gA + rowjump + kn, An + 2048 + wave * 512);
      gll16(gB + kn, Bn + wave * 512);
      gll16(gB + rowjump + kn, Bn + 2048 + wave * 512);
    }
    const unsigned short* Ac = As + (cur << 12);
    const unsigned short* Bc = Bs + (cur << 12);
    short8 af[4], bfr[4];
#pragma unroll
    for (int mt = 0; mt < 4; mt++)
      af[mt] = *(const short8*)(Ac + (wm * 64 + mt * 16 + lanelo) * 32 + quad * 8);
#pragma unroll
    for (int nt = 0; nt < 4; nt++)
      bfr[nt] = *(const short8*)(Bc + (wn * 64 + nt * 16 + lanelo) * 32 + quad * 8);
#pragma unroll
    for (int mt = 0; mt < 4; mt++)
#pragma unroll
      for (int nt = 0; nt < 4; nt++)
        acc[mt][nt] = mfma_bf16(af[mt], bfr[nt], acc[mt][nt]);
    __syncthreads();
    cur ^= 1;
  }
#pragma unroll
  for (int mt = 0; mt < 4; mt++) {
    int crow = m0 + wm * 64 + mt * 16 + quad * 4;
#pragma unroll
    for (int nt = 0; nt < 4; nt++) {
      int ccol = n0 + wn * 64 + nt * 16 + lanelo;
#pragma unroll
      for (int r = 0; r < 4; r++)
        C[(long)(crow + r) * N + ccol] = acc[mt][nt][r];
    }
  }
}

// ---------------- QKV GEMM with fused RoPE/cast/V-transpose epilogue ----------------
// A = xb (2048x2048 bf16), BT = WqkvT (3072x2048 bf16). No f32 intermediate.
// cols [0,2048): q -> RoPE -> qb (h,S,64) bf16
// cols [2048,2560): k -> RoPE -> kb (kvh,S,64) bf16
// cols [2560,3072): v -> vT (kvh,64,S) bf16 (transposed scatter)
// Region boundaries are 128-aligned => branch is block-uniform.
__global__ __launch_bounds__(256) void gemm_qkv(const unsigned short* __restrict__ A,
                                                const unsigned short* __restrict__ BT,
                                                const float* __restrict__ cosb,
                                                const float* __restrict__ sinb,
                                                unsigned short* __restrict__ qb,
                                                unsigned short* __restrict__ kb,
                                                unsigned short* __restrict__ vT) {
  __shared__ unsigned short As[2][4096];
  __shared__ unsigned short Bs[2][4096];
  const int K = 2048;
  int m0 = blockIdx.y * 128, n0 = blockIdx.x * 128;
  int tid = threadIdx.x;
  int lane = tid & 63, wave = tid >> 6;
  int quad = lane >> 4, lanelo = lane & 15;
  int wm = wave & 1, wn = wave >> 1;
  const unsigned short* gA = A + (long)(m0 + wave * 16 + (lane >> 2)) * K + (lane & 3) * 8;
  const unsigned short* gB = BT + (long)(n0 + wave * 16 + (lane >> 2)) * K + (lane & 3) * 8;
  long rowjump = (long)64 * K;
  f32x4 zero = {0.f, 0.f, 0.f, 0.f};
  f32x4 acc[4][4];
#pragma unroll
  for (int i = 0; i < 4; i++)
#pragma unroll
    for (int j = 0; j < 4; j++) acc[i][j] = zero;

  gll16(gA, &As[0][wave * 512]);
  gll16(gA + rowjump, &As[0][2048 + wave * 512]);
  gll16(gB, &Bs[0][wave * 512]);
  gll16(gB + rowjump, &Bs[0][2048 + wave * 512]);
  __syncthreads();

  int cur = 0;
  for (int k0 = 0; k0 < K; k0 += 32) {
    int kn = k0 + 32;
    if (kn < K) {
      gll16(gA + kn, &As[cur ^ 1][wave * 512]);
      gll16(gA + rowjump + kn, &As[cur ^ 1][2048 + wave * 512]);
      gll16(gB + kn, &Bs[cur ^ 1][wave * 512]);
      gll16(gB + rowjump + kn, &Bs[cur ^ 1][2048 + wave * 512]);
    }
    short8 af[4], bfr[4];
#pragma unroll
    for (int mt = 0; mt < 4; mt++)
      af[mt] = *(const short8*)(&As[cur][(wm * 64 + mt * 16 + lanelo) * 32 + quad * 8]);
#pragma unroll
    for (int nt = 0; nt < 4; nt++)
      bfr[nt] = *(const short8*)(&Bs[cur][(wn * 64 + nt * 16 + lanelo) * 32 + quad * 8]);
#pragma unroll
    for (int mt = 0; mt < 4; mt++)
#pragma unroll
      for (int nt = 0; nt < 4; nt++)
        acc[mt][nt] = mfma_bf16(af[mt], bfr[nt], acc[mt][nt]);
    __syncthreads();
    cur ^= 1;
  }

  int colbase = n0 + wn * 64;   // 64-aligned: wave's 64 cols = exactly one head
  if (colbase < 2560) {
    // q or k: RoPE pairs (d, d+32) are in (acc[mt][nt], acc[mt][nt+2]) within this lane
    unsigned short* dst;
    if (colbase < 2048) dst = qb + ((long)(colbase >> 6)) * S_LEN * HD;
    else                dst = kb + ((long)((colbase - 2048) >> 6)) * S_LEN * HD;
#pragma unroll
    for (int mt = 0; mt < 4; mt++) {
      int srow = m0 + wm * 64 + mt * 16 + quad * 4;
#pragma unroll
      for (int nt = 0; nt < 2; nt++) {
        int d = nt * 16 + lanelo;
#pragma unroll
        for (int r = 0; r < 4; r++) {
          int s = srow + r;
          float c  = cosb[s * HALFD + d];
          float sn = sinb[s * HALFD + d];
          float x1 = acc[mt][nt][r], x2 = acc[mt][nt + 2][r];
          dst[(long)s * HD + d]         = f2bf(x1 * c - x2 * sn);
          dst[(long)s * HD + d + HALFD] = f2bf(x2 * c + x1 * sn);
        }
      }
    }
  } else {
    // v: transposed scatter into vT (kvh, 64, S)
    unsigned short* vdst = vT + ((long)((colbase - 2560) >> 6)) * HD * S_LEN;
#pragma unroll
    for (int mt = 0; mt < 4; mt++) {
      int srow = m0 + wm * 64 + mt * 16 + quad * 4;
#pragma unroll
      for (int nt = 0; nt < 4; nt++) {
        int d = nt * 16 + lanelo;
#pragma unroll
        for (int r = 0; r < 4; r++)
          vdst[(long)d * S_LEN + srow + r] = f2bf(acc[mt][nt][r]);
      }
    }
  }
}

// ---------------- flash attention (no-max softmax): O (normalized) + 1/l per row ----------------
__global__ __launch_bounds__(256) void attn_flash(const unsigned short* __restrict__ qb,
                                                  const unsigned short* __restrict__ kb,
                                                  const unsigned short* __restrict__ vT,
                                                  const float* __restrict__ sinks,
                                                  unsigned short* __restrict__ ob,
                                                  float* __restrict__ linv) {
  __shared__ unsigned short plds[4][16 * 72];   // wave-private 16x64 bf16 P tile, stride 72
  int qt = 31 - blockIdx.x;                     // heavy tiles first
  int h = blockIdx.y, kvh = h >> 2;
  int lane = threadIdx.x & 63, wave = threadIdx.x >> 6;
  int quad = lane >> 4, lanelo = lane & 15;
  int q0 = qt * 64 + wave * 16;
  const unsigned short* qrow = qb + ((long)h * S_LEN + q0 + lanelo) * HD + quad * 8;
  short8 aq0 = *(const short8*)(qrow);
  short8 aq1 = *(const short8*)(qrow + HALFD);
  const unsigned short* kbase = kb + (long)kvh * S_LEN * HD;
  const unsigned short* vbase = vT + (long)kvh * HD * S_LEN;
  f32x4 zero = {0.f, 0.f, 0.f, 0.f};
  f32x4 oacc[4] = {zero, zero, zero, zero};
  float l[4] = {0.f, 0.f, 0.f, 0.f};
  unsigned short* pw = &plds[wave][0];

  for (int j0 = 0; j0 <= q0 + 15; j0 += 64) {
    f32x4 sc[4];
#pragma unroll
    for (int nd = 0; nd < 4; nd++) {
      const unsigned short* krow = kbase + (long)(j0 + nd * 16 + lanelo) * HD + quad * 8;
      short8 b0 = *(const short8*)(krow);
      short8 b1 = *(const short8*)(krow + HALFD);
      f32x4 c = mfma_bf16(aq0, b0, zero);
      sc[nd] = mfma_bf16(aq1, b1, c);
    }
#pragma unroll
    for (int nd = 0; nd < 4; nd++) {
      int col = j0 + nd * 16 + lanelo;
#pragma unroll
      for (int r = 0; r < 4; r++) {
        int row = q0 + quad * 4 + r;
        float e = (col <= row) ? __expf(sc[nd][r] * QKSCALE) : 0.f;
        l[r] += e;
        pw[(quad * 4 + r) * 72 + nd * 16 + lanelo] = f2bf(e);
      }
    }
    // wave-private LDS: no barrier needed, lgkmcnt ordering only
#pragma unroll
    for (int ks = 0; ks < 2; ks++) {
      short8 pa = *(const short8*)(&pw[lanelo * 72 + ks * 32 + quad * 8]);
#pragma unroll
      for (int nd = 0; nd < 4; nd++) {
        short8 vb = *(const short8*)(&vbase[(long)(nd * 16 + lanelo) * S_LEN + j0 + ks * 32 + quad * 8]);
        oacc[nd] = mfma_bf16(pa, vb, oacc[nd]);
      }
    }
  }
  float sink = sinks[h];
  float inv[4];
#pragma unroll
  for (int r = 0; r < 4; r++) {
    float s = l[r];
    s += __shfl_xor(s, 1, 64);
    s += __shfl_xor(s, 2, 64);
    s += __shfl_xor(s, 4, 64);
    s += __shfl_xor(s, 8, 64);
    s += __expf(sink);
    inv[r] = 1.f / s;
    if (lanelo == 0) linv[h * S_LEN + q0 + quad * 4 + r] = inv[r];
  }
#pragma unroll
  for (int nd = 0; nd < 4; nd++)
#pragma unroll
    for (int r = 0; r < 4; r++)
      ob[(long)(q0 + quad * 4 + r) * (NH * HD) + h * HD + nd * 16 + lanelo] = f2bf(oacc[nd][r] * inv[r]);
}

// ---------------- balanced prob writer body: recompute QK^T, p = exp(sc)*linv ----------------
__device__ __forceinline__ void probs_body(const unsigned short* __restrict__ qb,
                                           const unsigned short* __restrict__ kb,
                                           const float* __restrict__ linv,
                                           float* __restrict__ wout,
                                           int qt, int strip, int h, float* t) {
  int kvh = h >> 2;
  int lane = threadIdx.x & 63, wave = threadIdx.x >> 6;
  int quad = lane >> 4, lanelo = lane & 15;
  int q0 = qt * 64 + wave * 16;
  const unsigned short* qrow = qb + ((long)h * S_LEN + q0 + lanelo) * HD + quad * 8;
  short8 aq0 = *(const short8*)(qrow);
  short8 aq1 = *(const short8*)(qrow + HALFD);
  const unsigned short* kbase = kb + (long)kvh * S_LEN * HD;
  float inv[4];
#pragma unroll
  for (int r = 0; r < 4; r++) inv[r] = linv[h * S_LEN + q0 + quad * 4 + r];
  float* wb = wout + ((long)h * S_LEN + q0) * S_LEN;
  float* tw = t + wave * 1088;   // wave-private 16x64 f32 tile, stride 68
  f32x4 zero = {0.f, 0.f, 0.f, 0.f};
  int srow = lane >> 4, scol = (lane & 15) * 4;   // store mapping: 4 rows x 256B contiguous

  for (int jt = 0; jt < 8; jt++) {
    int j0 = strip * 512 + jt * 64;
    if (j0 > q0 + 15) {
      float4 z4 = {0.f, 0.f, 0.f, 0.f};
#pragma unroll
      for (int rg = 0; rg < 4; rg++)
        *(float4*)(&wb[(long)(rg * 4 + srow) * S_LEN + j0 + scol]) = z4;
      continue;
    }
    f32x4 sc[4];
#pragma unroll
    for (int nd = 0; nd < 4; nd++) {
      const unsigned short* krow = kbase + (long)(j0 + nd * 16 + lanelo) * HD + quad * 8;
      short8 b0 = *(const short8*)(krow);
      short8 b1 = *(const short8*)(krow + HALFD);
      f32x4 c = mfma_bf16(aq0, b0, zero);
      sc[nd] = mfma_bf16(aq1, b1, c);
    }
#pragma unroll
    for (int nd = 0; nd < 4; nd++) {
      int col = j0 + nd * 16 + lanelo;
#pragma unroll
      for (int r = 0; r < 4; r++) {
        int row = q0 + quad * 4 + r;
        float p = (col <= row) ? __expf(sc[nd][r] * QKSCALE) * inv[r] : 0.f;
        tw[(quad * 4 + r) * 68 + nd * 16 + lanelo] = p;
      }
    }
    // wave-private LDS transpose -> 256B-contiguous float4 stores
#pragma unroll
    for (int rg = 0; rg < 4; rg++) {
      int row = rg * 4 + srow;
      float4 v = *(float4*)(&tw[row * 68 + scol]);
      *(float4*)(&wb[(long)row * S_LEN + j0 + scol]) = v;
    }
  }
}

// ---------------- fused tail: blocks [0,256) = O-projection GEMM, [256,4352) = prob writer ----------------
__global__ __launch_bounds__(256) void tail_fused(const unsigned short* __restrict__ ob,
                                                  const unsigned short* __restrict__ WoT,
                                                  float* __restrict__ out,
                                                  const unsigned short* __restrict__ qb,
                                                  const unsigned short* __restrict__ kb,
                                                  const float* __restrict__ linv,
                                                  float* __restrict__ wout) {
  __shared__ __align__(16) char smem[32768];   // gemm: 2x(2x4096 ushort); probs: 4x1088 f32 (17408 B)
  int bid = blockIdx.x;
  if (bid < 256) {
    gemm128_body(ob, WoT, out, 2048, 2048, 2048, bid & 15, bid >> 4,
                 (unsigned short*)smem, (unsigned short*)(smem + 16384));
  } else {
    int id = bid - 256;
    probs_body(qb, kb, linv, wout, id & 31, (id >> 5) & 3, id >> 7, (float*)smem);
  }
}

extern "C" void kernel_launch(void* const* d_in, const int* in_sizes, int n_in,
                              void* d_out, int out_size, void* d_ws, size_t ws_size,
                              hipStream_t stream) {
  const float* x     = (const float*)d_in[0];
  const float* cosb  = (const float*)d_in[1];
  const float* sinb  = (const float*)d_in[2];
  const float* Wq    = (const float*)d_in[4];
  const float* Wk    = (const float*)d_in[5];
  const float* Wv    = (const float*)d_in[6];
  const float* Wo    = (const float*)d_in[7];
  const float* sinks = (const float*)d_in[8];
  float* out  = (float*)d_out;
  float* wout = out + (long)S_LEN * (NH * HD);   // attn_weights after attn_output

  char* w = (char*)d_ws;
  unsigned short* xb     = (unsigned short*)(w);                 // 8 MB (dead after gemm_qkv)
  float*          linv   = (float*)(w);                          // reuses xb after gemm_qkv
  unsigned short* WqkvT  = (unsigned short*)(w + (8l  << 20));   // 12 MB (3072 x 2048)
  unsigned short* WoT    = (unsigned short*)(w + (20l << 20));   // 8 MB
  unsigned short* qb     = (unsigned short*)(w + (28l << 20));   // 8 MB
  unsigned short* kb     = (unsigned short*)(w + (36l << 20));   // 2 MB
  unsigned short* vT     = (unsigned short*)(w + (38l << 20));   // 2 MB
  unsigned short* ob     = (unsigned short*)(w + (40l << 20));   // 8 MB

  // 1: cast + all weight transposes
  prologue<<<14336, 256, 0, stream>>>(x, xb, Wq, Wk, Wv, Wo, WqkvT, WoT);
  // 2: fused QKV projection + RoPE + bf16 cast + V transpose (no f32 intermediate)
  gemm_qkv<<<dim3(24, 16), 256, 0, stream>>>(xb, WqkvT, cosb, sinb, qb, kb, vT);
  // 3: flash attention
  attn_flash<<<dim3(32, 32), 256, 0, stream>>>(qb, kb, vT, sinks, ob, linv);
  // 4: fused O-projection GEMM (256 blocks) + prob writer (4096 blocks)
  tail_fused<<<4352, 256, 0, stream>>>(ob, WoT, out, qb, kb, linv, wout);
}